// Round 2
// 197.583 us; speedup vs baseline: 1.0246x; 1.0246x over previous
//
#include <hip/hip_runtime.h>
#include <math.h>

// CTC forward loss, linear-domain alpha recursion, power-of-2 renorm.
// B=256 -> one wave per batch/CU. Lane l owns states 4l..4l+3 (+ state 256
// as slot 4 on lane 63).
//
// Round-10 == Round-9 with the macro-arity compile fix (variadic indirection
// so K0..K3 bundles expand BEFORE SE/SO/TE parameter matching).
//
// R9 design recap: R8's step equilibrium (~105 cy) was set by the LDS
// write->gather chain being only 2 steps deep (step ~ L_ds/2). This round:
//  (a) 4-step read-ahead: gathers for row t+4 issued at step t into one of
//      FOUR read banks (k = t&3); ds_write runs 2 chunks ahead (rows t+4,t+5
//      written at even step t). Uniform s_waitcnt lgkmcnt(11) per step
//      (in-order DS queue: 11 newer ops at every step parity).
//  (b) packed-f32 recursion: P=(a0,a2) even states, Q=(a1,a3) odd states.
//      Both recursions share one shifted operand R=(x,a1), x = prev-lane a3.
//      v_pk_{add,fma,mul}_f32 cut ALPHA+CMT 15 -> 12 VALU (exact same
//      IEEE rounding as R8's scalar form).
// Global side unchanged: 16-chunk VGPR ring (v32-95), steady vmcnt(13)
// (write chunk t/2+2 at step t), 26-step HBM slack. Renorm every 8 steps,
// byte-identical to R8, regs renamed.
//
// ---- register map (inside the blob) --------------------------------------
// v10 global voffset  v11 LDS write addr  v12/v13 read addr label0/label1
// v14 blank base      v15 dummy           v30:31 L=(allow1,allow3)
// v32-95  16-chunk global queue (chunk c -> v[32+4*(c&15)])
// v96-110 4 read banks: k -> {lab0 v96+4k, lab1 v97+4k, blank v98+4k}
// v112:113 P=(a0,a2)  v114:115 Q=(a1,a3)  v116 a4  v117 tmp
// v118:119 R=(x,a1dup) v120:121 CB=(cb,cb) v122:123 C13=(c1,c3)
// v124:125 EPS pair    v126:127 t-pair / renorm scratch (v127)
// s90 loop counter, s91-95 renorm scratch

#define T_DIM 1024
#define C_DIM 128
#define U_DIM 128
#define LN2F  0.6931471805599453f

#define EPS_LIT "0x33d6bf95"   /* 1e-7f */

// c-multipliers for this step, from bank regs: CB=(cb,cb), C13=(c1,c3)
#define CMT(BP,BB) \
  "v_add_f32 v120, v124, " BB "\n\t" \
  "v_mov_b32 v121, v120\n\t" \
  "v_pk_add_f32 v[122:123], " BP ", v[124:125]\n\t"

// gather reads for row t+4 into bank k (issued AFTER CMT consumed bank k)
#define RD(B0,B1,B2,ROFF,RBOFF) \
  "ds_read_b32 " B0 ", v12 offset:" ROFF "\n\t" \
  "ds_read_b32 " B1 ", v13 offset:" ROFF "\n\t" \
  "ds_read_b32 " B2 ", v14 offset:" RBOFF "\n\t"

// packed alpha step:
//  t1 = Q+P = (a1+a0, a3+a2); t2 = R*L + t1; Q' = t2*(c1,c3)
//  P' = (P+R)*(cb,cb) = ((a0+x)*cb, (a2+a1)*cb); a4' = (a3+a4)*cb
#define ALPHA \
  "v_mov_b32_dpp v118, v115 wave_shr:1 row_mask:0xf bank_mask:0xf bound_ctrl:0\n\t" \
  "v_mov_b32 v119, v114\n\t" \
  "v_pk_add_f32 v[126:127], v[114:115], v[112:113]\n\t" \
  "v_pk_fma_f32 v[126:127], v[118:119], v[30:31], v[126:127]\n\t" \
  "v_pk_add_f32 v[112:113], v[112:113], v[118:119]\n\t" \
  "v_add_f32 v117, v115, v116\n\t" \
  "v_pk_mul_f32 v[114:115], v[126:127], v[122:123]\n\t" \
  "v_pk_mul_f32 v[112:113], v[112:113], v[120:121]\n\t" \
  "v_mul_f32 v116, v117, v120\n\t"

#define RENORM \
  "v_max_f32 v127, v112, v113\n\t" \
  "v_max_f32 v127, v127, v114\n\t" \
  "v_max_f32 v127, v127, v115\n\t" \
  "v_max_f32 v127, v127, v116\n\t" \
  "s_nop 1\n\t" \
  "v_max_f32_dpp v127, v127, v127 row_ror:8 row_mask:0xf bank_mask:0xf\n\t" \
  "s_nop 1\n\t" \
  "v_max_f32_dpp v127, v127, v127 row_ror:4 row_mask:0xf bank_mask:0xf\n\t" \
  "s_nop 1\n\t" \
  "v_max_f32_dpp v127, v127, v127 row_ror:2 row_mask:0xf bank_mask:0xf\n\t" \
  "s_nop 1\n\t" \
  "v_max_f32_dpp v127, v127, v127 row_ror:1 row_mask:0xf bank_mask:0xf\n\t" \
  "s_nop 1\n\t" \
  "v_readlane_b32 s91, v127, 0\n\t" \
  "v_readlane_b32 s92, v127, 16\n\t" \
  "v_readlane_b32 s93, v127, 32\n\t" \
  "v_readlane_b32 s94, v127, 48\n\t" \
  "s_nop 1\n\t" \
  "s_max_u32 s91, s91, s92\n\t" \
  "s_max_u32 s93, s93, s94\n\t" \
  "s_max_u32 s91, s91, s93\n\t" \
  "s_lshr_b32 s92, s91, 23\n\t" \
  "s_and_b32 s92, s92, 0xff\n\t" \
  "s_sub_u32 s93, 0x126, s92\n\t" \
  "s_min_u32 s93, s93, 0xfe\n\t" \
  "s_lshl_b32 s94, s93, 23\n\t" \
  "s_sub_u32 s95, 0x7f, s93\n\t" \
  "s_add_u32 %[EA], %[EA], s95\n\t" \
  "v_mul_f32 v112, s94, v112\n\t" \
  "v_mul_f32 v113, s94, v113\n\t" \
  "v_mul_f32 v114, s94, v114\n\t" \
  "v_mul_f32 v115, s94, v115\n\t" \
  "v_mul_f32 v116, s94, v116\n\t"

// Variadic indirection so the K0..K3 bundles expand BEFORE param matching.
#define SE(...) SE_X(__VA_ARGS__)
#define SO(...) SO_X(__VA_ARGS__)
#define TE(...) TE_X(__VA_ARGS__)

// Even step (steady): wait oldest-needed chunk, write chunk (rows t+4,t+5),
// load chunk t/2+16, commit row t (bank k), issue reads row t+4 (same bank).
// For SE the read row offset == write offset (row t+4 = chunk's row 0).
#define SE_X(QW,WOFF,QL,B0,B1,B2,BP,RBOFF) \
  "s_waitcnt vmcnt(13)\n\t" \
  "ds_write_b128 v11, v[" QW "] offset:" WOFF "\n\t" \
  "global_load_dwordx4 v[" QL "], v10, %[P]\n\t" \
  "v_add_u32 v10, 0x400, v10\n\t" \
  "s_waitcnt lgkmcnt(11)\n\t" \
  CMT(BP,B2) RD(B0,B1,B2,WOFF,RBOFF) ALPHA

// Odd step: commit row t (bank k), issue reads row t+4 (same bank).
#define SO_X(B0,B1,B2,BP,ROFF,RBOFF) \
  "s_waitcnt lgkmcnt(11)\n\t" \
  CMT(BP,B2) RD(B0,B1,B2,ROFF,RBOFF) ALPHA

// Tail even step (no more global loads; descending vmcnt).
#define TE_X(VC,QW,WOFF,B0,B1,B2,BP,RBOFF) \
  "s_waitcnt vmcnt(" VC ")\n\t" \
  "ds_write_b128 v11, v[" QW "] offset:" WOFF "\n\t" \
  "s_waitcnt lgkmcnt(11)\n\t" \
  CMT(BP,B2) RD(B0,B1,B2,WOFF,RBOFF) ALPHA

// Final drain steps: no writes, no reads, descending lgkmcnt.
#define FN(LGK,BP,BB) \
  "s_waitcnt lgkmcnt(" LGK ")\n\t" \
  CMT(BP,BB) ALPHA

// bank register name bundles (k = t & 3)
#define K0 "v96","v97","v98","v[96:97]"
#define K1 "v100","v101","v102","v[100:101]"
#define K2 "v104","v105","v106","v[104:105]"
#define K3 "v108","v109","v110","v[108:109]"

__global__ __launch_bounds__(64) void ctc_alpha_kernel(
    const int*   __restrict__ y_true,   // (B, U) int32
    const float* __restrict__ y_pred,   // (B, T, C) f32 softmax probs
    float*       __restrict__ out,      // (B, 1) f32
    int B)
{
  __shared__ float4 ldsbuf[1024];       // 16 KB: 32-row x 512 B ring

  const int b = blockIdx.x;
  if (b >= B) return;
  const int lane = threadIdx.x;           // 0..63
  const float* __restrict__ p  = y_pred + (size_t)b * (T_DIM * C_DIM);
  const int*   __restrict__ yb = y_true + b * U_DIM;
  const int blank = C_DIM - 1;

  // Labels for this lane's odd states: s=4l+1 -> u=2l ; s=4l+3 -> u=2l+1
  const int ylab0 = yb[2 * lane];
  const int ylab1 = yb[2 * lane + 1];
  int yprev = blank;
  if (lane > 0) yprev = yb[2 * lane - 1];
  const float allow1 = (lane > 0 && ylab0 != blank && ylab0 != yprev) ? 1.0f : 0.0f;
  const float allow3 = (ylab1 != blank && ylab1 != ylab0)             ? 1.0f : 0.0f;

  const unsigned lds_off = (unsigned)(uintptr_t)(void*)ldsbuf;
  const int gvoff = lane * 16;                    // global: lane slice of a 1KB chunk
  const int wraddr = (int)lds_off + lane * 16;    // LDS write addr
  const int rd1    = (int)lds_off + ylab0 * 4;    // LDS read addr, label0
  const int rd3    = (int)lds_off + ylab1 * 4;    // LDS read addr, label1
  const int rdb    = (int)lds_off;                // blank via offset imm +508

  // Virtual init: alpha_{-1}=1 on lane0 makes t=0 a uniform step.
  const float init0 = (lane == 0) ? 1.0f : 0.0f;
  float a3out, a4out;
  int   e_acc = 0;

  asm volatile(
    // ---- prologue ------------------------------------------------------
    "s_mov_b32 m0, -1\n\t"
    "v_mov_b32 v10, %[GV]\n\t"
    "v_mov_b32 v11, %[WA]\n\t"
    "v_mov_b32 v12, %[R1]\n\t"
    "v_mov_b32 v13, %[R3]\n\t"
    "v_mov_b32 v14, %[RB]\n\t"
    "v_mov_b32 v30, %[L1]\n\t"
    "v_mov_b32 v31, %[L3]\n\t"
    "v_mov_b32 v112, %[I0]\n\t"
    "v_mov_b32 v113, 0\n\t"
    "v_mov_b32 v114, 0\n\t"
    "v_mov_b32 v115, 0\n\t"
    "v_mov_b32 v116, 0\n\t"
    "v_mov_b32 v124, " EPS_LIT "\n\t"
    "v_mov_b32 v125, " EPS_LIT "\n\t"
    // prefill 16 chunks (rows 0..31)
    "global_load_dwordx4 v[32:35], v10, %[P]\n\t" "v_add_u32 v10, 0x400, v10\n\t"
    "global_load_dwordx4 v[36:39], v10, %[P]\n\t" "v_add_u32 v10, 0x400, v10\n\t"
    "global_load_dwordx4 v[40:43], v10, %[P]\n\t" "v_add_u32 v10, 0x400, v10\n\t"
    "global_load_dwordx4 v[44:47], v10, %[P]\n\t" "v_add_u32 v10, 0x400, v10\n\t"
    "global_load_dwordx4 v[48:51], v10, %[P]\n\t" "v_add_u32 v10, 0x400, v10\n\t"
    "global_load_dwordx4 v[52:55], v10, %[P]\n\t" "v_add_u32 v10, 0x400, v10\n\t"
    "global_load_dwordx4 v[56:59], v10, %[P]\n\t" "v_add_u32 v10, 0x400, v10\n\t"
    "global_load_dwordx4 v[60:63], v10, %[P]\n\t" "v_add_u32 v10, 0x400, v10\n\t"
    "global_load_dwordx4 v[64:67], v10, %[P]\n\t" "v_add_u32 v10, 0x400, v10\n\t"
    "global_load_dwordx4 v[68:71], v10, %[P]\n\t" "v_add_u32 v10, 0x400, v10\n\t"
    "global_load_dwordx4 v[72:75], v10, %[P]\n\t" "v_add_u32 v10, 0x400, v10\n\t"
    "global_load_dwordx4 v[76:79], v10, %[P]\n\t" "v_add_u32 v10, 0x400, v10\n\t"
    "global_load_dwordx4 v[80:83], v10, %[P]\n\t" "v_add_u32 v10, 0x400, v10\n\t"
    "global_load_dwordx4 v[84:87], v10, %[P]\n\t" "v_add_u32 v10, 0x400, v10\n\t"
    "global_load_dwordx4 v[88:91], v10, %[P]\n\t" "v_add_u32 v10, 0x400, v10\n\t"
    "global_load_dwordx4 v[92:95], v10, %[P]\n\t" "v_add_u32 v10, 0x400, v10\n\t"
    // chunks 0,1 -> LDS rows 0..3; prime gathers for rows 0..3 (banks 0..3).
    // Two dummy reads pad the in-order DS queue so the steady lgkmcnt(11)
    // wait fully drains rows 0/1 at steps t=0,1.
    "s_waitcnt vmcnt(15)\n\t"
    "ds_write_b128 v11, v[32:35] offset:0\n\t"
    "s_waitcnt vmcnt(14)\n\t"
    "ds_write_b128 v11, v[36:39] offset:1024\n\t"
    "ds_read_b32 v96, v12 offset:0\n\t"
    "ds_read_b32 v97, v13 offset:0\n\t"
    "ds_read_b32 v98, v14 offset:508\n\t"
    "ds_read_b32 v15, v14 offset:508\n\t"          // dummy
    "ds_read_b32 v100, v12 offset:512\n\t"
    "ds_read_b32 v101, v13 offset:512\n\t"
    "ds_read_b32 v102, v14 offset:1020\n\t"
    "ds_read_b32 v15, v14 offset:508\n\t"          // dummy
    "ds_read_b32 v104, v12 offset:1024\n\t"
    "ds_read_b32 v105, v13 offset:1024\n\t"
    "ds_read_b32 v106, v14 offset:1532\n\t"
    "ds_read_b32 v108, v12 offset:1536\n\t"
    "ds_read_b32 v109, v13 offset:1536\n\t"
    "ds_read_b32 v110, v14 offset:2044\n\t"
    // ---- main loop: 31 superblocks x 32 steps = steps 0..991 ----------
    "s_mov_b32 s90, 31\n"
    "LM_%=:\n\t"
    SE("40:43","2048","32:35",K0,"2556")   SO(K1,"2560","3068")
    SE("44:47","3072","36:39",K2,"3580")   SO(K3,"3584","4092")
    SE("48:51","4096","40:43",K0,"4604")   SO(K1,"4608","5116")
    SE("52:55","5120","44:47",K2,"5628")   SO(K3,"5632","6140")   RENORM
    SE("56:59","6144","48:51",K0,"6652")   SO(K1,"6656","7164")
    SE("60:63","7168","52:55",K2,"7676")   SO(K3,"7680","8188")
    SE("64:67","8192","56:59",K0,"8700")   SO(K1,"8704","9212")
    SE("68:71","9216","60:63",K2,"9724")   SO(K3,"9728","10236")  RENORM
    SE("72:75","10240","64:67",K0,"10748") SO(K1,"10752","11260")
    SE("76:79","11264","68:71",K2,"11772") SO(K3,"11776","12284")
    SE("80:83","12288","72:75",K0,"12796") SO(K1,"12800","13308")
    SE("84:87","13312","76:79",K2,"13820") SO(K3,"13824","14332") RENORM
    SE("88:91","14336","80:83",K0,"14844") SO(K1,"14848","15356")
    SE("92:95","15360","84:87",K2,"15868") SO(K3,"15872","16380")
    SE("32:35","0","88:91",K0,"508")       SO(K1,"512","1020")
    SE("36:39","1024","92:95",K2,"1532")   SO(K3,"1536","2044")   RENORM
    "s_sub_u32 s90, s90, 1\n\t"
    "s_cmp_lg_u32 s90, 0\n\t"
    "s_cbranch_scc1 LM_%=\n\t"
    // ---- tail: steps 992..1019 (no more global loads) ------------------
    TE("13","40:43","2048",K0,"2556")   SO(K1,"2560","3068")
    TE("12","44:47","3072",K2,"3580")   SO(K3,"3584","4092")
    TE("11","48:51","4096",K0,"4604")   SO(K1,"4608","5116")
    TE("10","52:55","5120",K2,"5628")   SO(K3,"5632","6140")   RENORM
    TE("9","56:59","6144",K0,"6652")    SO(K1,"6656","7164")
    TE("8","60:63","7168",K2,"7676")    SO(K3,"7680","8188")
    TE("7","64:67","8192",K0,"8700")    SO(K1,"8704","9212")
    TE("6","68:71","9216",K2,"9724")    SO(K3,"9728","10236")  RENORM
    TE("5","72:75","10240",K0,"10748")  SO(K1,"10752","11260")
    TE("4","76:79","11264",K2,"11772")  SO(K3,"11776","12284")
    TE("3","80:83","12288",K0,"12796")  SO(K1,"12800","13308")
    TE("2","84:87","13312",K2,"13820")  SO(K3,"13824","14332") RENORM
    TE("1","88:91","14336",K0,"14844")  SO(K1,"14848","15356")
    TE("0","92:95","15360",K2,"15868")  SO(K3,"15872","16380")
    // steps 1020..1023: pure compute, drain the DS queue
    FN("10","v[96:97]","v98")
    FN("7","v[100:101]","v102")
    FN("3","v[104:105]","v106")
    FN("0","v[108:109]","v110")
    RENORM
    // ---- epilogue: move results out ------------------------------------
    "v_mov_b32 %[O3], v115\n\t"
    "v_mov_b32 %[O4], v116\n\t"
    : [O3]"=v"(a3out), [O4]"=v"(a4out), [EA]"+s"(e_acc)
    : [P]"s"(p), [GV]"v"(gvoff), [WA]"v"(wraddr), [R1]"v"(rd1), [R3]"v"(rd3),
      [RB]"v"(rdb), [L1]"v"(allow1), [L3]"v"(allow3), [I0]"v"(init0)
    : "v10","v11","v12","v13","v14","v15","v30","v31",
      "v32","v33","v34","v35","v36","v37","v38","v39","v40","v41","v42","v43",
      "v44","v45","v46","v47","v48","v49","v50","v51","v52","v53","v54","v55",
      "v56","v57","v58","v59","v60","v61","v62","v63","v64","v65","v66","v67",
      "v68","v69","v70","v71","v72","v73","v74","v75","v76","v77","v78","v79",
      "v80","v81","v82","v83","v84","v85","v86","v87","v88","v89","v90","v91",
      "v92","v93","v94","v95","v96","v97","v98","v100","v101","v102",
      "v104","v105","v106","v108","v109","v110","v112",
      "v113","v114","v115","v116","v117","v118","v119","v120","v121","v122",
      "v123","v124","v125","v126","v127",
      "s90","s91","s92","s93","s94","s95","scc","memory");

  if (lane == 63) {
    float s = a3out + a4out;           // alpha[255] + alpha[256]
    s = fmaxf(s, 1e-37f);
    float ll = logf(s) + (float)e_acc * LN2F;
    out[b] = -ll;
  }
}

extern "C" void kernel_launch(void* const* d_in, const int* in_sizes, int n_in,
                              void* d_out, int out_size, void* d_ws, size_t ws_size,
                              hipStream_t stream) {
  const int*   y_true = (const int*)d_in[0];
  const float* y_pred = (const float*)d_in[1];
  float*       out    = (float*)d_out;
  const int B = in_sizes[0] / U_DIM;   // 256
  ctc_alpha_kernel<<<dim3(B), dim3(64), 0, stream>>>(y_true, y_pred, out, B);
}